// Round 4
// baseline (1070.238 us; speedup 1.0000x reference)
//
#include <hip/hip_runtime.h>

typedef __attribute__((ext_vector_type(4))) float f32x4;
typedef __attribute__((ext_vector_type(8))) short bf16x8;
typedef __attribute__((ext_vector_type(8))) unsigned short ushort8;
typedef unsigned short u16;
typedef unsigned int u32;

__device__ __forceinline__ u16 f2b(float f) {
    u32 u = __builtin_bit_cast(u32, f);
    u32 r = (u + 0x7fffu + ((u >> 16) & 1u)) >> 16;
    return (u16)r;
}

// ---------------------------------------------------------------------------
// Weight prep: fp32 [K,N] -> bf16 [N,K] (transposed), optional scale
// ---------------------------------------------------------------------------
struct PrepAll {
    const float* src[8];
    u16* dst[8];
    int K[8];
    int N[8];
    float S[8];
};

__global__ __launch_bounds__(256) void prep_w(PrepAll p) {
    const int wi = blockIdx.y;
    const int K = p.K[wi], N = p.N[wi];
    const int e = blockIdx.x * 256 + threadIdx.x;
    if (e >= K * N) return;
    const int k = e / N, n = e % N;
    p.dst[wi][n * K + k] = f2b(p.src[wi][e] * p.S[wi]);
}

__global__ __launch_bounds__(64) void prep_bias(const float* __restrict__ t1,
                                                const float* __restrict__ t2,
                                                float* __restrict__ Bm) {
    const int j = threadIdx.x;
    const int i = blockIdx.x;
    const int hh = blockIdx.y;
    const int s = hh >> 3, h = hh & 7;
    const int idx = ((i >> 3) - (j >> 3) + 7) * 15 + ((i & 7) - (j & 7) + 7);
    const float* tab = s ? t2 : t1;
    Bm[(long)hh * 4096 + i * 64 + j] = tab[idx * 8 + h];
}

__global__ __launch_bounds__(256) void prep_bcat(const float* __restrict__ q1b,
                                                 const float* __restrict__ kv1b,
                                                 const float* __restrict__ q2b,
                                                 float qs, float* __restrict__ b1cat,
                                                 float* __restrict__ q2bs) {
    const int g = blockIdx.x * 256 + threadIdx.x;
    if (g < 256) {
        b1cat[g] = qs * q1b[g];
        q2bs[g] = qs * q2b[g];
    } else if (g < 768) {
        b1cat[g] = kv1b[g - 256];
    }
}

__global__ __launch_bounds__(256) void cast_bf(const float* __restrict__ in,
                                               u16* __restrict__ out) {
    const long i = (long)blockIdx.x * 256 + threadIdx.x;
    const float4 a = *(const float4*)(in + i * 8);
    const float4 b = *(const float4*)(in + i * 8 + 4);
    ushort8 o;
    o[0] = f2b(a.x); o[1] = f2b(a.y); o[2] = f2b(a.z); o[3] = f2b(a.w);
    o[4] = f2b(b.x); o[5] = f2b(b.y); o[6] = f2b(b.z); o[7] = f2b(b.w);
    *(ushort8*)(out + i * 8) = o;
}

__global__ __launch_bounds__(256) void ln256(const float* __restrict__ x,
                                             const float* __restrict__ g,
                                             const float* __restrict__ b,
                                             u16* __restrict__ out) {
    const int lane = threadIdx.x & 63;
    const long row = (long)blockIdx.x * 4 + (threadIdx.x >> 6);
    const float4 v = *(const float4*)(x + row * 256 + lane * 4);
    float s = v.x + v.y + v.z + v.w;
    float s2 = v.x * v.x + v.y * v.y + v.z * v.z + v.w * v.w;
#pragma unroll
    for (int off = 32; off > 0; off >>= 1) {
        s += __shfl_xor(s, off);
        s2 += __shfl_xor(s2, off);
    }
    const float mu = s * (1.f / 256.f);
    const float var = s2 * (1.f / 256.f) - mu * mu;
    const float rr = rsqrtf(var + 1e-5f);
    const int c = lane * 4;
    const float4 gv = *(const float4*)(g + c);
    const float4 bv = *(const float4*)(b + c);
    ushort4 o;
    o.x = f2b((v.x - mu) * rr * gv.x + bv.x);
    o.y = f2b((v.y - mu) * rr * gv.y + bv.y);
    o.z = f2b((v.z - mu) * rr * gv.z + bv.z);
    o.w = f2b((v.w - mu) * rr * gv.w + bv.w);
    *(ushort4*)(out + row * 256 + c) = o;
}

// ---------------------------------------------------------------------------
// Barrier-free-K bf16 GEMM. Block = 256 rows x 64 cols, 4 waves stacked on M.
// Weight panel Bt[64 cols][K] lives in LDS (stride 264 u16, conflict-free
// b128 reads); A streams global->fragment registers directly (no LDS, no
// barriers in the K loop; 3-step prefetch keeps ~12 loads/wave in flight).
// Epilogue: transpose C through per-wave LDS region -> coalesced dwordx4.
// EPI: 0 = bias -> bf16 | 2 = gelu(bias) -> bf16 | 3 = bias + res -> fp32
// K = KTILES*256; grid 1-D, %8==0, XCD-chunked n-fastest swizzle.
// ---------------------------------------------------------------------------
template <int EPI, int KTILES>
__global__ __launch_bounds__(256, 3) void wgemm(const u16* __restrict__ A,
                                                const u16* __restrict__ Bt,
                                                const float* __restrict__ bias,
                                                const float* __restrict__ res,
                                                u16* __restrict__ outb,
                                                float* __restrict__ outf,
                                                int N, int Nt) {
    constexpr int K = KTILES * 256;
    constexpr int STEPS = KTILES * 8;
    __shared__ u16 LDSU[18432];  // B-panel [64][264] (33.8KB) / epi 4x4608

    const int t = threadIdx.x, lane = t & 63, wave = t >> 6;
    const int l15 = lane & 15, lg = lane >> 4;

    const int per = gridDim.x >> 3;
    const int id2 = (blockIdx.x & 7) * per + (blockIdx.x >> 3);
    const int bm = id2 / Nt, bn = id2 % Nt;
    const long m0 = (long)bm * 256;
    const int n0 = bn * 64;

    const u16* Aw = A + (m0 + wave * 64 + l15) * K + lg * 8;
    const int brow = t >> 2;
    const u16* Bg = Bt + (long)(n0 + brow) * K + (t & 3) * 64;

    f32x4 acc[4][4];
#pragma unroll
    for (int i = 0; i < 4; i++)
#pragma unroll
        for (int j = 0; j < 4; j++) acc[i][j] = (f32x4){0.f, 0.f, 0.f, 0.f};

    bf16x8 af[3][4];
    auto lda = [&](int set, int s) {
#pragma unroll
        for (int mi = 0; mi < 4; mi++)
            af[set][mi] = *(const bf16x8*)(Aw + (long)mi * 16 * K + s * 32);
    };

    auto loadB = [&](int kc, bool first) {
        if (!first) __builtin_amdgcn_s_barrier();  // prior reads drained via MFMA deps
        bf16x8 tmp[4];
#pragma unroll
        for (int half = 0; half < 2; half++) {
#pragma unroll
            for (int j = 0; j < 4; j++)
                tmp[j] = *(const bf16x8*)(Bg + kc * 256 + half * 32 + j * 8);
#pragma unroll
            for (int j = 0; j < 4; j++)
                *(bf16x8*)&LDSU[brow * 264 + (t & 3) * 64 + half * 32 + j * 8] = tmp[j];
        }
        asm volatile("s_waitcnt lgkmcnt(0)" ::: "memory");
        __builtin_amdgcn_sched_barrier(0);
        __builtin_amdgcn_s_barrier();
    };

    lda(0, 0);
    lda(1, 1);
    lda(2, 2);

#pragma unroll
    for (int s = 0; s < STEPS; ++s) {
        if ((s & 7) == 0) loadB(s >> 3, s == 0);
        bf16x8 bfr[4];
#pragma unroll
        for (int ni = 0; ni < 4; ni++)
            bfr[ni] = *(const bf16x8*)&LDSU[(ni * 16 + l15) * 264 + (s & 7) * 32 + lg * 8];
#pragma unroll
        for (int mi = 0; mi < 4; mi++)
#pragma unroll
            for (int ni = 0; ni < 4; ni++)
                acc[mi][ni] = __builtin_amdgcn_mfma_f32_16x16x32_bf16(af[s % 3][mi], bfr[ni], acc[mi][ni], 0, 0, 0);
        if (s + 3 < STEPS) lda(s % 3, s + 3);
    }

    __builtin_amdgcn_s_barrier();  // B-panel region now reusable for epilogue
    const long rowbase = m0 + wave * 64 + lane;

    if (EPI == 3) {
        float* EF = (float*)&LDSU[wave * 4608];  // [64][36] f32, col-halves
#pragma unroll
        for (int p = 0; p < 2; p++) {
#pragma unroll
            for (int mi = 0; mi < 4; mi++) {
#pragma unroll
                for (int nh = 0; nh < 2; nh++) {
                    const int ni = p * 2 + nh;
                    const float bv = bias[n0 + ni * 16 + l15];
#pragma unroll
                    for (int r = 0; r < 4; r++)
                        EF[(mi * 16 + lg * 4 + r) * 36 + nh * 16 + l15] = acc[mi][ni][r] + bv;
                }
            }
            asm volatile("s_waitcnt lgkmcnt(0)" ::: "memory");
            __builtin_amdgcn_sched_barrier(0);
#pragma unroll
            for (int j = 0; j < 8; j++) {
                f32x4 cv = *(f32x4*)&EF[lane * 36 + j * 4];
                const long idx = rowbase * N + n0 + p * 32 + j * 4;
                const float4 rv = *(const float4*)(res + idx);
                f32x4 ov;
                ov[0] = cv[0] + rv.x; ov[1] = cv[1] + rv.y;
                ov[2] = cv[2] + rv.z; ov[3] = cv[3] + rv.w;
                *(f32x4*)(outf + idx) = ov;
            }
            if (p == 0) {
                asm volatile("s_waitcnt lgkmcnt(0)" ::: "memory");
                __builtin_amdgcn_sched_barrier(0);
            }
        }
    } else {
        u16* E = &LDSU[wave * 4608];  // [64][72] u16
#pragma unroll
        for (int mi = 0; mi < 4; mi++) {
#pragma unroll
            for (int ni = 0; ni < 4; ni++) {
                const float bv = bias[n0 + ni * 16 + l15];
#pragma unroll
                for (int r = 0; r < 4; r++) {
                    float v = acc[mi][ni][r] + bv;
                    if (EPI == 2) v = 0.5f * v * (1.f + erff(v * 0.70710678118f));
                    E[(mi * 16 + lg * 4 + r) * 72 + ni * 16 + l15] = f2b(v);
                }
            }
        }
        asm volatile("s_waitcnt lgkmcnt(0)" ::: "memory");
        __builtin_amdgcn_sched_barrier(0);
#pragma unroll
        for (int j = 0; j < 8; j++) {
            bf16x8 cv = *(bf16x8*)&E[lane * 72 + j * 8];
            *(bf16x8*)(outb + rowbase * N + n0 + j * 8) = cv;
        }
    }
}

// ---------------------------------------------------------------------------
// Windowed attention: one wave per (window, head). N=64 tokens, hd=32.
// ---------------------------------------------------------------------------
__global__ __launch_bounds__(256) void attn64(const u16* __restrict__ Q, int qs,
                                              const u16* __restrict__ KV, int ks,
                                              const float* __restrict__ Bm,
                                              u16* __restrict__ AO) {
    __shared__ u16 Plds[4][64 * 72];
    __shared__ u16 Vt[4][32 * 72];
    const int lane = threadIdx.x & 63, wave = threadIdx.x >> 6;
    const int wh = blockIdx.x * 4 + wave;
    const int w = wh >> 3, h = wh & 7;
    const int b = w / 400, rem = w % 400;
    const int wy = rem / 20, wx = rem % 20;
    const long base_t = (long)b * 25600 + wy * 8 * 160 + wx * 8;
    const int l15 = lane & 15, lg = lane >> 4;

    bf16x8 qf[4], kf[4];
#pragma unroll
    for (int ti = 0; ti < 4; ti++) {
        const int r = ti * 16 + l15;
        const long tt = base_t + (r >> 3) * 160 + (r & 7);
        qf[ti] = *(const bf16x8*)(Q + tt * qs + h * 32 + lg * 8);
        kf[ti] = *(const bf16x8*)(KV + tt * ks + h * 32 + lg * 8);
    }
    const f32x4 zz = (f32x4){0.f, 0.f, 0.f, 0.f};
    f32x4 s[4][4];
#pragma unroll
    for (int ti = 0; ti < 4; ti++)
#pragma unroll
        for (int tj = 0; tj < 4; tj++)
            s[ti][tj] = __builtin_amdgcn_mfma_f32_16x16x32_bf16(qf[ti], kf[tj], zz, 0, 0, 0);

    {
        const long tt = base_t + (lane >> 3) * 160 + (lane & 7);
        const u16* vrow = KV + tt * ks + 256 + h * 32;
#pragma unroll
        for (int cg = 0; cg < 4; cg++) {
            bf16x8 v8 = *(const bf16x8*)(vrow + cg * 8);
#pragma unroll
            for (int j = 0; j < 8; j++) Vt[wave][(cg * 8 + j) * 72 + lane] = (u16)v8[j];
        }
    }

    const float* Bh = Bm + h * 4096;
#pragma unroll
    for (int ti = 0; ti < 4; ti++) {
#pragma unroll
        for (int r = 0; r < 4; r++) {
            const int i = ti * 16 + lg * 4 + r;
            float vv[4];
            float m = -1e30f;
#pragma unroll
            for (int tj = 0; tj < 4; tj++) {
                vv[tj] = s[ti][tj][r] + Bh[i * 64 + tj * 16 + l15];
                m = fmaxf(m, vv[tj]);
            }
#pragma unroll
            for (int off = 1; off < 16; off <<= 1) m = fmaxf(m, __shfl_xor(m, off));
            float sum = 0.f;
#pragma unroll
            for (int tj = 0; tj < 4; tj++) {
                vv[tj] = __expf(vv[tj] - m);
                sum += vv[tj];
            }
#pragma unroll
            for (int off = 1; off < 16; off <<= 1) sum += __shfl_xor(sum, off);
            const float inv = 1.f / sum;
#pragma unroll
            for (int tj = 0; tj < 4; tj++)
                Plds[wave][i * 72 + tj * 16 + l15] = f2b(vv[tj] * inv);
        }
    }

    f32x4 o[4][2];
#pragma unroll
    for (int mi = 0; mi < 4; mi++)
#pragma unroll
        for (int n = 0; n < 2; n++) o[mi][n] = zz;
#pragma unroll
    for (int c = 0; c < 2; c++) {
        bf16x8 vf[2];
#pragma unroll
        for (int n = 0; n < 2; n++)
            vf[n] = *(const bf16x8*)(&Vt[wave][(n * 16 + l15) * 72 + c * 32 + lg * 8]);
#pragma unroll
        for (int mi = 0; mi < 4; mi++) {
            bf16x8 pf = *(const bf16x8*)(&Plds[wave][(mi * 16 + l15) * 72 + c * 32 + lg * 8]);
#pragma unroll
            for (int n = 0; n < 2; n++)
                o[mi][n] = __builtin_amdgcn_mfma_f32_16x16x32_bf16(pf, vf[n], o[mi][n], 0, 0, 0);
        }
    }
#pragma unroll
    for (int mi = 0; mi < 4; mi++) {
#pragma unroll
        for (int n = 0; n < 2; n++) {
#pragma unroll
            for (int r = 0; r < 4; r++) {
                const int i = mi * 16 + lg * 4 + r;
                const long tt = base_t + (i >> 3) * 160 + (i & 7);
                AO[tt * 256 + h * 32 + n * 16 + l15] = f2b(o[mi][n][r]);
            }
        }
    }
}

// ---------------------------------------------------------------------------
extern "C" void kernel_launch(void* const* d_in, const int* in_sizes, int n_in,
                              void* d_out, int out_size, void* d_ws, size_t ws_size,
                              hipStream_t stream) {
    const float* x    = (const float*)d_in[0];
    const float* enc  = (const float*)d_in[1];
    const float* n1g  = (const float*)d_in[3];
    const float* n1b  = (const float*)d_in[4];
    const float* q1w  = (const float*)d_in[5];
    const float* q1b  = (const float*)d_in[6];
    const float* kv1w = (const float*)d_in[7];
    const float* kv1b = (const float*)d_in[8];
    const float* bias1 = (const float*)d_in[9];
    const float* p1w  = (const float*)d_in[10];
    const float* p1b  = (const float*)d_in[11];
    const float* q2w  = (const float*)d_in[12];
    const float* q2b  = (const float*)d_in[13];
    const float* kv2w = (const float*)d_in[14];
    const float* kv2b = (const float*)d_in[15];
    const float* bias2 = (const float*)d_in[16];
    const float* p2w  = (const float*)d_in[17];
    const float* p2b  = (const float*)d_in[18];
    const float* n2g  = (const float*)d_in[19];
    const float* n2b  = (const float*)d_in[20];
    const float* f1w  = (const float*)d_in[21];
    const float* f1b  = (const float*)d_in[22];
    const float* f2w  = (const float*)d_in[23];
    const float* f2bias = (const float*)d_in[24];
    float* out = (float*)d_out;

    char* ws = (char*)d_ws;
    size_t off = 0;
    auto alloc = [&](size_t bytes) {
        char* p = ws + off;
        off += (bytes + 255) & ~(size_t)255;
        return p;
    };
    u16* Wt    = (u16*)alloc(1048576 * 2);
    float* Bm  = (float*)alloc(16 * 4096 * 4);
    float* b1c = (float*)alloc(768 * 4);
    float* q2s = (float*)alloc(256 * 4);
    u16* xn    = (u16*)alloc(52428800);   // LN1 out; then y1
    u16* qb    = (u16*)alloc(52428800);   // qkv part 1 / Q2 / LN2 out
    u16* kvb   = (u16*)alloc(104857600);  // qkv part 2 / KV2 / MLP hidden
    u16* ao    = (u16*)alloc(52428800);   // attn out
    u16* encb  = (u16*)alloc(52428800);   // enc_feat bf16

    u16* qkv = qb;   // [102400][768] contiguous across qb+kvb
    u16* h1  = kvb;  // MLP hidden chunk [51200][1024]

    u16 *q1t = Wt, *p1t = Wt + 196608, *q2t = Wt + 262144,
        *kv2t = Wt + 327680, *p2t = Wt + 458752, *f1t = Wt + 524288, *f2t = Wt + 786432;

    const float qscale = 0.17677669529663687f;  // 32^-0.5

    PrepAll pa;
    pa.src[0] = q1w;  pa.dst[0] = q1t;        pa.K[0] = 256;  pa.N[0] = 256;  pa.S[0] = qscale;
    pa.src[1] = kv1w; pa.dst[1] = Wt + 65536; pa.K[1] = 256;  pa.N[1] = 512;  pa.S[1] = 1.f;
    pa.src[2] = p1w;  pa.dst[2] = p1t;        pa.K[2] = 256;  pa.N[2] = 256;  pa.S[2] = 1.f;
    pa.src[3] = q2w;  pa.dst[3] = q2t;        pa.K[3] = 256;  pa.N[3] = 256;  pa.S[3] = qscale;
    pa.src[4] = kv2w; pa.dst[4] = kv2t;       pa.K[4] = 256;  pa.N[4] = 512;  pa.S[4] = 1.f;
    pa.src[5] = p2w;  pa.dst[5] = p2t;        pa.K[5] = 256;  pa.N[5] = 256;  pa.S[5] = 1.f;
    pa.src[6] = f1w;  pa.dst[6] = f1t;        pa.K[6] = 256;  pa.N[6] = 1024; pa.S[6] = 1.f;
    pa.src[7] = f2w;  pa.dst[7] = f2t;        pa.K[7] = 1024; pa.N[7] = 256;  pa.S[7] = 1.f;
    prep_w<<<dim3(1024, 8), 256, 0, stream>>>(pa);
    prep_bias<<<dim3(64, 16), 64, 0, stream>>>(bias1, bias2, Bm);
    prep_bcat<<<dim3(3), 256, 0, stream>>>(q1b, kv1b, q2b, qscale, b1c, q2s);
    cast_bf<<<dim3(12800), 256, 0, stream>>>(enc, encb);
    ln256<<<dim3(25600), 256, 0, stream>>>(x, n1g, n1b, xn);

    // stage 1: fused QKV gemm (Q pre-scaled), attn, proj
    wgemm<0, 1><<<dim3(4800), 256, 0, stream>>>(xn, q1t, b1c, nullptr, qkv, nullptr, 768, 12);
    attn64<<<dim3(3200), 256, 0, stream>>>(qkv, 768, qkv + 256, 768, Bm, ao);
    wgemm<0, 1><<<dim3(1600), 256, 0, stream>>>(ao, p1t, p1b, nullptr, xn, nullptr, 256, 4);

    // stage 2: cross-attention to encoder features
    wgemm<0, 1><<<dim3(1600), 256, 0, stream>>>(xn, q2t, q2s, nullptr, qb, nullptr, 256, 4);
    wgemm<0, 1><<<dim3(3200), 256, 0, stream>>>(encb, kv2t, kv2b, nullptr, kvb, nullptr, 512, 8);
    attn64<<<dim3(3200), 256, 0, stream>>>(qb, 256, kvb, 512, Bm + 8 * 4096, ao);

    // proj2 + shortcut residual -> fp32 in d_out
    wgemm<3, 1><<<dim3(1600), 256, 0, stream>>>(ao, p2t, p2b, x, nullptr, out, 256, 4);

    // MLP: LN2 -> fc1+gelu -> fc2+residual (in-place), 2 row-chunks
    ln256<<<dim3(25600), 256, 0, stream>>>(out, n2g, n2b, qb);
    for (int c = 0; c < 2; c++) {
        const u16* xh = qb + (size_t)c * 51200 * 256;
        float* oc = out + (size_t)c * 51200 * 256;
        wgemm<2, 1><<<dim3(3200), 256, 0, stream>>>(xh, f1t, f1b, nullptr, h1, nullptr, 1024, 16);
        wgemm<3, 4><<<dim3(800), 256, 0, stream>>>(h1, f2t, f2bias, oc, nullptr, oc, 256, 4);
    }
}